// Round 5
// baseline (461.718 us; speedup 1.0000x reference)
//
#include <hip/hip_runtime.h>
#include <hip/hip_bf16.h>

#define TB 2
#define TT 4096
#define TC 2048
#define TM 8192          // B*T
#define THD 64
#define TNCH 64          // chunks per batch

typedef __attribute__((ext_vector_type(8))) short bf16x8;
typedef __attribute__((ext_vector_type(4))) float f32x4;

__device__ __forceinline__ float us2f(unsigned short u){
    union { unsigned int u; float f; } x; x.u = ((unsigned int)u) << 16; return x.f;
}
__device__ __forceinline__ unsigned short f2us(float f){
    unsigned int u = __float_as_uint(f);
    unsigned int r = (u + 0x7fffu + ((u >> 16) & 1u)) >> 16;   // RNE bf16
    return (unsigned short)r;
}

// ---------------- generic fp32 -> bf16 convert ----------------
__global__ void k_cvt(const float* __restrict__ src, unsigned short* __restrict__ dst, int n4){
    int i = blockIdx.x * 256 + threadIdx.x;
    if (i < n4){
        float4 v = *(const float4*)(src + (size_t)i * 4);
        ushort4 u; u.x = f2us(v.x); u.y = f2us(v.y); u.z = f2us(v.z); u.w = f2us(v.w);
        *(ushort4*)(dst + (size_t)i * 4) = u;
    }
}

// ---------------- w2 [160][2048] f32 -> w2T [2048][160] bf16 ----------------
__global__ __launch_bounds__(256) void k_tw2(const float* __restrict__ w2, unsigned short* __restrict__ w2T){
    __shared__ float Ts[160][33];
    int tid = threadIdx.x, ct = blockIdx.x;   // 64 blocks of 32 c
    for (int i = tid; i < 5120; i += 256){
        int r = i >> 5, c = i & 31;
        Ts[r][c] = w2[(size_t)r * TC + ct * 32 + c];
    }
    __syncthreads();
    for (int i = tid; i < 5120; i += 256){
        int c = i / 160, fd = i % 160;
        w2T[(size_t)(ct * 32 + c) * 160 + fd] = f2us(Ts[fd][c]);
    }
}

// ---------------- W[c][j] f32 -> WT[f][j][c] bf16, f-order {dw1,Wk,Wv,Wg,Wr} ----------------
__global__ __launch_bounds__(256) void k_tw5(
    const float* __restrict__ s0, const float* __restrict__ s1,
    const float* __restrict__ s2, const float* __restrict__ s3,
    const float* __restrict__ s4, unsigned short* __restrict__ WT)
{
    __shared__ float Ts[32][65];
    int tid = threadIdx.x, ct = blockIdx.x, f = blockIdx.y;
    const float* src = (f == 0) ? s0 : (f == 1) ? s1 : (f == 2) ? s2 : (f == 3) ? s3 : s4;
    for (int i = tid; i < 2048; i += 256){
        int r = i >> 6, j = i & 63;
        Ts[r][j] = src[(size_t)(ct * 32 + r) * THD + j];
    }
    __syncthreads();
    for (int i = tid; i < 2048; i += 256){
        int j = i >> 5, r = i & 31;
        WT[(size_t)f * 131072 + (size_t)j * TC + ct * 32 + r] = f2us(Ts[r][j]);
    }
}

// ---------------- zero rbuf..dpre (5 x 2 MiB contiguous) ----------------
__global__ void k_zero(float* __restrict__ p){
    int i = blockIdx.x * 256 + threadIdx.x;   // 655360 float4
    if (i < 655360){
        float4 z = {0.f, 0.f, 0.f, 0.f};
        *(float4*)(p + (size_t)i * 4) = z;
    }
}

// ---------------- lx = hs[:, -1] ----------------
__global__ void k_lx(const float* __restrict__ hs, float* __restrict__ o){
    int i = blockIdx.x * 256 + threadIdx.x;
    if (i < TB * TC){
        int b = i >> 11, c = i & (TC - 1);
        o[i] = hs[((size_t)(b * TT + TT - 1)) * TC + c];
    }
}

// ---------------- gemm1 MFMA: Gpart[kc] = xxx[64n x 256k] @ w1b[256k x 160] ----------------
__global__ __launch_bounds__(256) void k_gemm1_mfma(
    const float* __restrict__ hs, const float* __restrict__ shift,
    const float* __restrict__ maax, const unsigned short* __restrict__ w1b,
    float* __restrict__ Gpart)
{
    __shared__ unsigned short As[64 * 40];    // [m][k] pad 40
    __shared__ unsigned short Bs[160 * 40];   // [n][k] pad 40
    int tid = threadIdx.x;
    int wv = tid >> 6, ln = tid & 63;
    int lm = ln & 15, lq = ln >> 4;
    int n0 = blockIdx.x * 64;
    int c0 = blockIdx.y * 256;
    f32x4 zero = {0.f, 0.f, 0.f, 0.f};
    f32x4 acc[10];
#pragma unroll
    for (int i = 0; i < 10; ++i) acc[i] = zero;

    for (int step = 0; step < 8; ++step){
        int kk0 = c0 + step * 32;
        {   // A staging: xxx on the fly
            int m = tid >> 2, kg = (tid & 3) * 8;
            int n = n0 + m; int t = n & (TT - 1); int b = n >> 12;
            const float* hp = hs + (size_t)n * TC + kk0 + kg;
            const float* pp = (t == 0) ? (shift + (size_t)b * TC + kk0 + kg) : (hp - TC);
            float4 h0 = *(const float4*)hp,      h1 = *(const float4*)(hp + 4);
            float4 p0 = *(const float4*)pp,      p1 = *(const float4*)(pp + 4);
            float4 m0 = *(const float4*)(maax + kk0 + kg), m1 = *(const float4*)(maax + kk0 + kg + 4);
            ushort4 ua, ub;
            ua.x = f2us(h0.x + (p0.x - h0.x) * m0.x);
            ua.y = f2us(h0.y + (p0.y - h0.y) * m0.y);
            ua.z = f2us(h0.z + (p0.z - h0.z) * m0.z);
            ua.w = f2us(h0.w + (p0.w - h0.w) * m0.w);
            ub.x = f2us(h1.x + (p1.x - h1.x) * m1.x);
            ub.y = f2us(h1.y + (p1.y - h1.y) * m1.y);
            ub.z = f2us(h1.z + (p1.z - h1.z) * m1.z);
            ub.w = f2us(h1.w + (p1.w - h1.w) * m1.w);
            *(ushort4*)(As + m * 40 + kg) = ua;
            *(ushort4*)(As + m * 40 + kg + 4) = ub;
        }
        for (int i = tid; i < 640; i += 256){
            int k = i / 20, ng = i % 20;
            uint4 w4 = *(const uint4*)(w1b + (size_t)(kk0 + k) * 160 + ng * 8);
            const unsigned short* ww = (const unsigned short*)&w4;
#pragma unroll
            for (int j = 0; j < 8; ++j) Bs[(ng * 8 + j) * 40 + k] = ww[j];
        }
        __syncthreads();
        bf16x8 af = *(const bf16x8*)(As + (wv * 16 + lm) * 40 + lq * 8);
#pragma unroll
        for (int nt = 0; nt < 10; ++nt){
            bf16x8 bf_ = *(const bf16x8*)(Bs + (nt * 16 + lm) * 40 + lq * 8);
            acc[nt] = __builtin_amdgcn_mfma_f32_16x16x32_bf16(af, bf_, acc[nt], 0, 0, 0);
        }
        __syncthreads();
    }
    float* gp = Gpart + (size_t)blockIdx.y * TM * 160;
#pragma unroll
    for (int nt = 0; nt < 10; ++nt)
#pragma unroll
        for (int i = 0; i < 4; ++i){
            int n = n0 + wv * 16 + lq * 4 + i;
            gp[(size_t)n * 160 + nt * 16 + lm] = acc[nt][i];
        }
}

// ---------------- G1b = bf16(tanh(sum Gpart)) ----------------
__global__ void k_g1tanh(const float* __restrict__ Gpart, unsigned short* __restrict__ G1b){
    int i = blockIdx.x * 256 + threadIdx.x;   // 327680 groups of 4
    if (i < 327680){
        float4 s = {0.f, 0.f, 0.f, 0.f};
        for (int kc = 0; kc < 8; ++kc){
            float4 g = *(const float4*)(Gpart + (size_t)kc * TM * 160 + (size_t)i * 4);
            s.x += g.x; s.y += g.y; s.z += g.z; s.w += g.w;
        }
        ushort4 o;
        o.x = f2us(tanhf(s.x)); o.y = f2us(tanhf(s.y));
        o.z = f2us(tanhf(s.z)); o.w = f2us(tanhf(s.w));
        *(ushort4*)(G1b + (size_t)i * 4) = o;
    }
}

// ---------------- fused mix+proj ----------------
// grid (128 m-tiles of 64, 4 K-quarters of 512), 256 thr (4 waves)
// per chunk: mix-MFMA -> X vals in regs -> per-wave LDS tile -> proj-MFMA accumulate
// outputs f-order: {dpre, kbuf, vbuf, gpre, rbuf} via atomicAdd (pre-zeroed)
__global__ __launch_bounds__(256, 2) void k_mixproj(
    const float* __restrict__ hs, const float* __restrict__ shift,
    const unsigned short* __restrict__ G1b, const unsigned short* __restrict__ w2T,
    const unsigned short* __restrict__ WT,
    const float* __restrict__ maaw, const float* __restrict__ maak,
    const float* __restrict__ maav, const float* __restrict__ maar,
    const float* __restrict__ maag,
    float* __restrict__ dpre, float* __restrict__ kbuf, float* __restrict__ vbuf,
    float* __restrict__ gpre, float* __restrict__ rbuf)
{
    __shared__ float Hs[65][72];              // rows n0-1 .. n0+63 of hs (prev+cur)
    __shared__ unsigned short Xs[64 * 72];    // per-wave-private 16-row slices
    int tid = threadIdx.x;
    int wv = tid >> 6, ln = tid & 63;
    int lm = ln & 15, lq = ln >> 4;
    int n0 = blockIdx.x * 64;
    int kh = blockIdx.y;

    // G1 A-fragments (bf16, per f) — row = n0 + wv*16 + lm
    bf16x8 af_g1[5];
    {
        const unsigned short* gp = G1b + (size_t)(n0 + wv * 16 + lm) * 160 + lq * 8;
#pragma unroll
        for (int f = 0; f < 5; ++f) af_g1[f] = *(const bf16x8*)(gp + f * 32);
    }

    const float* mas[5] = {maaw, maak, maav, maar, maag};
    f32x4 zero = {0.f, 0.f, 0.f, 0.f};
    f32x4 accp[5][4];
#pragma unroll
    for (int f = 0; f < 5; ++f)
#pragma unroll
        for (int jt = 0; jt < 4; ++jt) accp[f][jt] = zero;

    for (int ch = 0; ch < 8; ++ch){
        int c0 = kh * 512 + ch * 64;
        __syncthreads();                      // protect Hs from prior-iter readers
        for (int i = tid; i < 1040; i += 256){
            int r = i >> 4, g = (i & 15) * 4;
            const float* src;
            if (r == 0){
                src = ((n0 & (TT - 1)) == 0) ? (shift + (size_t)(n0 >> 12) * TC + c0 + g)
                                             : (hs + (size_t)(n0 - 1) * TC + c0 + g);
            } else {
                src = hs + (size_t)(n0 + r - 1) * TC + c0 + g;
            }
            *(float4*)&Hs[r][g] = *(const float4*)src;
        }
        __syncthreads();

        // hoist h / (p-h) for this wave's 16 rows x 64 cols slice
        float hv[4][4], dv[4][4];
#pragma unroll
        for (int ct = 0; ct < 4; ++ct){
            int lc = ct * 16 + lm;
#pragma unroll
            for (int i = 0; i < 4; ++i){
                int lr = wv * 16 + lq * 4 + i;
                float h = Hs[lr + 1][lc];
                float p = Hs[lr][lc];
                hv[ct][i] = h; dv[ct][i] = p - h;
            }
        }

#pragma unroll
        for (int f = 0; f < 5; ++f){
            // mix MFMA: m_f tile (C-layout)
            f32x4 macc[4];
#pragma unroll
            for (int ct = 0; ct < 4; ++ct){
                bf16x8 bf_ = *(const bf16x8*)(w2T + (size_t)(c0 + ct * 16 + lm) * 160 + f * 32 + lq * 8);
                macc[ct] = __builtin_amdgcn_mfma_f32_16x16x32_bf16(af_g1[f], bf_, zero, 0, 0, 0);
            }
            // X values -> per-wave LDS slice (in-wave LDS ordering guarantees visibility)
#pragma unroll
            for (int ct = 0; ct < 4; ++ct){
                float ma = mas[f][c0 + ct * 16 + lm];
#pragma unroll
                for (int i = 0; i < 4; ++i){
                    float xv = hv[ct][i] + dv[ct][i] * (ma + macc[ct][i]);
                    Xs[(wv * 16 + lq * 4 + i) * 72 + ct * 16 + lm] = f2us(xv);
                }
            }
            // proj MFMA: accumulate X @ W_f
#pragma unroll
            for (int ks = 0; ks < 2; ++ks){
                bf16x8 af = *(const bf16x8*)(Xs + (wv * 16 + lm) * 72 + ks * 32 + lq * 8);
#pragma unroll
                for (int jt = 0; jt < 4; ++jt){
                    bf16x8 bf_ = *(const bf16x8*)(WT + (size_t)f * 131072
                                   + (size_t)(jt * 16 + lm) * TC + c0 + ks * 32 + lq * 8);
                    accp[f][jt] = __builtin_amdgcn_mfma_f32_16x16x32_bf16(af, bf_, accp[f][jt], 0, 0, 0);
                }
            }
        }
    }

    float* outs[5] = {dpre, kbuf, vbuf, gpre, rbuf};
#pragma unroll
    for (int f = 0; f < 5; ++f)
#pragma unroll
        for (int jt = 0; jt < 4; ++jt)
#pragma unroll
            for (int i = 0; i < 4; ++i){
                int n = n0 + wv * 16 + lq * 4 + i;
                atomicAdd(outs[f] + (size_t)n * THD + jt * 16 + lm, accp[f][jt][i]);
            }
}

// ---------------- logw = -exp(time_decay + tanh(dpre) @ dw2) ----------------
__global__ __launch_bounds__(256) void k_wdecay(
    const float* __restrict__ dpre, const float* __restrict__ dw2,
    const float* __restrict__ tdec, float* __restrict__ logwb)
{
    __shared__ float W2s[64][65];
    __shared__ float Ths[16][65];
    int tid = threadIdx.x;
    int n0 = blockIdx.x * 16;
    for (int i = 0; i < 16; ++i){
        int flat = i * 256 + tid;
        W2s[flat >> 6][flat & 63] = dw2[flat];
    }
    for (int i = 0; i < 4; ++i){
        int flat = i * 256 + tid;
        int tt = flat >> 6, j = flat & 63;
        Ths[tt][j] = tanhf(dpre[(size_t)(n0 + tt) * THD + j]);
    }
    __syncthreads();
    int hh = tid & 63, tg = tid >> 6;
    float td = tdec[hh];
#pragma unroll
    for (int ii = 0; ii < 4; ++ii){
        int tt = tg * 4 + ii;
        float a = 0.f;
#pragma unroll 8
        for (int j = 0; j < 64; ++j) a += Ths[tt][j] * W2s[j][hh];
        logwb[(size_t)(n0 + tt) * THD + hh] = -expf(td + a);
    }
}

// ---------------- scan pass A ----------------
__global__ __launch_bounds__(256) void k_scanA(
    const float* __restrict__ kbuf, const float* __restrict__ vbuf,
    const float* __restrict__ logwb,
    float* __restrict__ chI, float* __restrict__ chP)
{
    __shared__ float kl[32][65], vl[32][65], ewl[32][65];
    int tid = threadIdx.x;
    int b = blockIdx.x >> 6, ch = blockIdx.x & 63;
    int w = tid >> 6, v = tid & 63, kb = w * 16;
    float s[16];
#pragma unroll
    for (int i = 0; i < 16; ++i) s[i] = 0.f;
    float p = 1.f;
    for (int ph = 0; ph < 2; ++ph){
        int t0 = b * TT + ch * 64 + ph * 32;
        for (int i = 0; i < 8; ++i){
            int flat = i * 256 + tid;
            int tt = flat >> 6, j = flat & 63;
            size_t g = (size_t)(t0 + tt) * THD + j;
            kl[tt][j] = kbuf[g];
            vl[tt][j] = vbuf[g];
            ewl[tt][j] = expf(logwb[g]);
        }
        __syncthreads();
        if (tid < 64){
#pragma unroll 8
            for (int t = 0; t < 32; ++t) p *= ewl[t][tid];
        }
        for (int t = 0; t < 32; ++t){
            float vv = vl[t][v];
#pragma unroll
            for (int i = 0; i < 16; ++i){
                float e = ewl[t][kb + i], kk = kl[t][kb + i];
                s[i] = s[i] * e + kk * vv;
            }
        }
        __syncthreads();
    }
    size_t base = ((size_t)(b * TNCH + ch)) * THD * THD;
#pragma unroll
    for (int i = 0; i < 16; ++i) chI[base + (size_t)(kb + i) * THD + v] = s[i];
    if (tid < 64) chP[(size_t)(b * TNCH + ch) * THD + tid] = p;
}

// ---------------- scan pass B (prefetched) ----------------
__global__ __launch_bounds__(256) void k_scanB(
    const float* __restrict__ chI, const float* __restrict__ chP,
    const float* __restrict__ wkv0,
    float* __restrict__ chS0, float* __restrict__ sfin)
{
    int tid = threadIdx.x;
    int b = blockIdx.x;
    int w = tid >> 6, v = tid & 63, kb = w * 16;
    float s[16], P[16], I[16], Pn[16], In[16];
#pragma unroll
    for (int i = 0; i < 16; ++i)
        s[i] = wkv0[(size_t)b * THD * THD + (size_t)(kb + i) * THD + v];
    {
        size_t base = (size_t)(b * TNCH);
#pragma unroll
        for (int i = 0; i < 16; ++i){
            P[i] = chP[base * THD + kb + i];
            I[i] = chI[base * THD * THD + (size_t)(kb + i) * THD + v];
        }
    }
    for (int ch = 0; ch < TNCH; ++ch){
        if (ch < TNCH - 1){
            size_t basen = (size_t)(b * TNCH + ch + 1);
#pragma unroll
            for (int i = 0; i < 16; ++i){
                Pn[i] = chP[basen * THD + kb + i];
                In[i] = chI[basen * THD * THD + (size_t)(kb + i) * THD + v];
            }
        }
        size_t base = (size_t)(b * TNCH + ch);
#pragma unroll
        for (int i = 0; i < 16; ++i){
            chS0[base * THD * THD + (size_t)(kb + i) * THD + v] = s[i];
            s[i] = s[i] * P[i] + I[i];
        }
#pragma unroll
        for (int i = 0; i < 16; ++i){ P[i] = Pn[i]; I[i] = In[i]; }
    }
#pragma unroll
    for (int i = 0; i < 16; ++i)
        sfin[(size_t)b * THD * THD + (size_t)(kb + i) * THD + v] = s[i];
}

// ---------------- scan pass C ----------------
__global__ __launch_bounds__(256) void k_scanC(
    const float* __restrict__ rbuf, const float* __restrict__ kbuf,
    const float* __restrict__ vbuf, const float* __restrict__ logwb,
    const float* __restrict__ chS0, const float* __restrict__ faaaa,
    float* __restrict__ obuf)
{
    __shared__ float rl[32][65], kl[32][65], vl[32][65], ewl[32][65];
    __shared__ float part[4][64];
    __shared__ float ruk[32];
    __shared__ float ul[64];
    int tid = threadIdx.x;
    int b = blockIdx.x >> 6, ch = blockIdx.x & 63;
    int w = tid >> 6, v = tid & 63, kb = w * 16;
    if (tid < 64) ul[tid] = faaaa[tid];
    float s[16];
    {
        size_t base = ((size_t)(b * TNCH + ch)) * THD * THD;
#pragma unroll
        for (int i = 0; i < 16; ++i) s[i] = chS0[base + (size_t)(kb + i) * THD + v];
    }
    for (int ph = 0; ph < 2; ++ph){
        int t0 = b * TT + ch * 64 + ph * 32;
        for (int i = 0; i < 8; ++i){
            int flat = i * 256 + tid;
            int tt = flat >> 6, j = flat & 63;
            size_t g = (size_t)(t0 + tt) * THD + j;
            rl[tt][j] = rbuf[g];
            kl[tt][j] = kbuf[g];
            vl[tt][j] = vbuf[g];
            ewl[tt][j] = expf(logwb[g]);
        }
        __syncthreads();
        if (tid < 32){
            float a = 0.f;
#pragma unroll 8
            for (int k = 0; k < 64; ++k) a += rl[tid][k] * ul[k] * kl[tid][k];
            ruk[tid] = a;
        }
        __syncthreads();
        for (int t = 0; t < 32; ++t){
            float vv = vl[t][v];
            float pp = 0.f;
#pragma unroll
            for (int i = 0; i < 16; ++i) pp += rl[t][kb + i] * s[i];
            part[w][v] = pp;
            __syncthreads();
            if (w == 0){
                float o = part[0][v] + part[1][v] + part[2][v] + part[3][v] + ruk[t] * vv;
                obuf[(size_t)(t0 + t) * THD + v] = o;
            }
#pragma unroll
            for (int i = 0; i < 16; ++i){
                float e = ewl[t][kb + i], kk = kl[t][kb + i];
                s[i] = s[i] * e + kk * vv;
            }
            __syncthreads();
        }
    }
}

// ---------------- out MFMA: out = (o*silu(g)) @ Wo ----------------
__global__ __launch_bounds__(256) void k_out_mfma(
    const float* __restrict__ obuf, const float* __restrict__ gpre,
    const unsigned short* __restrict__ Wob, float* __restrict__ outp)
{
    __shared__ unsigned short As[64 * 72];    // [m][k=64] pad 72
    __shared__ unsigned short Bs[128 * 72];   // [n][k=64] pad 72
    int tid = threadIdx.x;
    int wv = tid >> 6, ln = tid & 63;
    int lm = ln & 15, lq = ln >> 4;
    int n0 = blockIdx.x * 64, c0 = blockIdx.y * 128;

    for (int i = tid; i < 1024; i += 256){
        int r = i >> 4, g = i & 15;
        size_t base = (size_t)(n0 + r) * THD + g * 4;
        float4 ov = *(const float4*)(obuf + base);
        float4 gv = *(const float4*)(gpre + base);
        ushort4 u;
        u.x = f2us(ov.x * (gv.x / (1.f + expf(-gv.x))));
        u.y = f2us(ov.y * (gv.y / (1.f + expf(-gv.y))));
        u.z = f2us(ov.z * (gv.z / (1.f + expf(-gv.z))));
        u.w = f2us(ov.w * (gv.w / (1.f + expf(-gv.w))));
        *(ushort4*)(As + r * 72 + g * 4) = u;
    }
    for (int i = tid; i < 1024; i += 256){
        int k = i >> 4, ng = i & 15;
        uint4 w4 = *(const uint4*)(Wob + (size_t)k * TC + c0 + ng * 8);
        const unsigned short* ww = (const unsigned short*)&w4;
#pragma unroll
        for (int j = 0; j < 8; ++j) Bs[(ng * 8 + j) * 72 + k] = ww[j];
    }
    __syncthreads();

    f32x4 zero = {0.f, 0.f, 0.f, 0.f};
    f32x4 acc[8];
#pragma unroll
    for (int i = 0; i < 8; ++i) acc[i] = zero;
#pragma unroll
    for (int ks = 0; ks < 2; ++ks){
        bf16x8 af = *(const bf16x8*)(As + (wv * 16 + lm) * 72 + ks * 32 + lq * 8);
#pragma unroll
        for (int nt = 0; nt < 8; ++nt){
            bf16x8 bf_ = *(const bf16x8*)(Bs + (nt * 16 + lm) * 72 + ks * 32 + lq * 8);
            acc[nt] = __builtin_amdgcn_mfma_f32_16x16x32_bf16(af, bf_, acc[nt], 0, 0, 0);
        }
    }
#pragma unroll
    for (int nt = 0; nt < 8; ++nt)
#pragma unroll
        for (int i = 0; i < 4; ++i){
            int n = n0 + wv * 16 + lq * 4 + i;
            outp[(size_t)n * TC + c0 + nt * 16 + lm] = acc[nt][i];
        }
}

extern "C" void kernel_launch(void* const* d_in, const int* in_sizes, int n_in,
                              void* d_out, int out_size, void* d_ws, size_t ws_size,
                              hipStream_t stream)
{
    const float* hs    = (const float*)d_in[0];
    const float* shift = (const float*)d_in[1];
    const float* wkv0  = (const float*)d_in[2];
    const float* maax  = (const float*)d_in[3];
    const float* maaw  = (const float*)d_in[4];
    const float* maak  = (const float*)d_in[5];
    const float* maav  = (const float*)d_in[6];
    const float* maar  = (const float*)d_in[7];
    const float* maag  = (const float*)d_in[8];
    const float* w1    = (const float*)d_in[9];
    const float* w2    = (const float*)d_in[10];
    const float* tdec  = (const float*)d_in[11];
    const float* dw1   = (const float*)d_in[12];
    const float* dw2   = (const float*)d_in[13];
    const float* faaaa = (const float*)d_in[14];
    const float* Wr    = (const float*)d_in[15];
    const float* Wk    = (const float*)d_in[16];
    const float* Wv    = (const float*)d_in[17];
    const float* Wg    = (const float*)d_in[18];
    const float* Wo    = (const float*)d_in[19];

    if (ws_size < 67000000ULL) return;

    char* ws = (char*)d_ws;
    unsigned short* w1b  = (unsigned short*)(ws + 0);          // 2048x160 bf16
    unsigned short* w2T  = (unsigned short*)(ws + 655360);     // 2048x160 bf16 (transposed)
    unsigned short* WT   = (unsigned short*)(ws + 1310720);    // 5x64x2048 bf16 {dw1,Wk,Wv,Wg,Wr}
    unsigned short* Wob  = (unsigned short*)(ws + 2621440);    // 64x2048 bf16
    unsigned short* G1b  = (unsigned short*)(ws + 2883584);    // 8192x160 bf16
    float*          Gpart= (float*)(ws + 5505024);             // 8x8192x160 f32
    float*          rbuf = (float*)(ws + 47448064);
    float*          kbuf = (float*)(ws + 49545216);
    float*          vbuf = (float*)(ws + 51642368);
    float*          gpre = (float*)(ws + 53739520);
    float*          dpre = (float*)(ws + 55836672);
    float*          logwb= (float*)(ws + 57933824);
    float*          obuf = (float*)(ws + 60030976);
    float*          chI  = (float*)(ws + 62128128);
    float*          chS0 = (float*)(ws + 64225280);
    float*          chP  = (float*)(ws + 66322432);

    float* outp = (float*)d_out;
    float* lxp  = outp + (size_t)TM * TC;
    float* sfin = lxp + (size_t)TB * TC;

    k_cvt  <<<320, 256, 0, stream>>>(w1, w1b, 81920);
    k_tw2  <<<64, 256, 0, stream>>>(w2, w2T);
    k_tw5  <<<dim3(64, 5), 256, 0, stream>>>(dw1, Wk, Wv, Wg, Wr, WT);
    k_cvt  <<<128, 256, 0, stream>>>(Wo, Wob, 32768);
    k_zero <<<2560, 256, 0, stream>>>(rbuf);
    k_lx   <<<16, 256, 0, stream>>>(hs, lxp);

    k_gemm1_mfma <<<dim3(128, 8), 256, 0, stream>>>(hs, shift, maax, w1b, Gpart);
    k_g1tanh     <<<1280, 256, 0, stream>>>(Gpart, G1b);
    k_mixproj    <<<dim3(128, 4), 256, 0, stream>>>(hs, shift, G1b, w2T, WT,
                                                    maaw, maak, maav, maar, maag,
                                                    dpre, kbuf, vbuf, gpre, rbuf);
    k_wdecay     <<<512, 256, 0, stream>>>(dpre, dw2, tdec, logwb);
    k_scanA      <<<128, 256, 0, stream>>>(kbuf, vbuf, logwb, chI, chP);
    k_scanB      <<<2, 256, 0, stream>>>(chI, chP, wkv0, chS0, sfin);
    k_scanC      <<<128, 256, 0, stream>>>(rbuf, kbuf, vbuf, logwb, chS0, faaaa, obuf);
    k_out_mfma   <<<dim3(128, 16), 256, 0, stream>>>(obuf, gpre, Wob, outp);
}